// Round 6
// baseline (781.206 us; speedup 1.0000x reference)
//
#include <hip/hip_runtime.h>
#include <stdint.h>

#define NEGF (-1.0e8f)
#define NCELL (512 * 512)
#define INVLN2 1.4426950408889634f
#define KD 16
#define NIV 64

// raw barrier: LDS ordering only (never drains vmcnt)
#define BAR() asm volatile("s_waitcnt lgkmcnt(0)\n\ts_barrier" ::: "memory")

__device__ __forceinline__ float exp2f_(float x) {
#if __has_builtin(__builtin_amdgcn_exp2f)
  return __builtin_amdgcn_exp2f(x);
#else
  return exp2f(x);
#endif
}
__device__ __forceinline__ float log2f_(float x) {
#if __has_builtin(__builtin_amdgcn_logf)
  return __builtin_amdgcn_logf(x);
#else
  return log2f(x);
#endif
}
__device__ __forceinline__ uint32_t pknorm16(float a, float b) {
#if __has_builtin(__builtin_amdgcn_cvt_pknorm_u16)
  typedef unsigned short u2v __attribute__((ext_vector_type(2)));
  union { u2v v; uint32_t u; } cv;
  cv.v = __builtin_amdgcn_cvt_pknorm_u16(a, b);
  return cv.u;
#else
  uint32_t pa = (uint32_t)(a * 65535.0f + 0.5f);
  uint32_t pb = (uint32_t)(b * 65535.0f + 0.5f);
  return pa | (pb << 16);
#endif
}

// DPP wave shifts (gfx9 family): 0x138 wave_shr:1 (lane l <- l-1), 0x130 wave_shl:1 (lane l <- l+1)
__device__ __forceinline__ float dpp_shr1_f(float src, float old0) {
  return __int_as_float(__builtin_amdgcn_update_dpp(
      __float_as_int(old0), __float_as_int(src), 0x138, 0xF, 0xF, false));
}
__device__ __forceinline__ float dpp_shl1_f(float src, float old63) {
  return __int_as_float(__builtin_amdgcn_update_dpp(
      __float_as_int(old63), __float_as_int(src), 0x130, 0xF, 0xF, false));
}
__device__ __forceinline__ uint32_t dpp_shl1_u(uint32_t src, uint32_t old63) {
  return (uint32_t)__builtin_amdgcn_update_dpp((int)old63, (int)src, 0x130, 0xF, 0xF, false);
}
__device__ __forceinline__ float rdlane_f(float v, int l) {
  return __int_as_float(__builtin_amdgcn_readlane(__float_as_int(v), l));
}
__device__ __forceinline__ uint32_t rdlane_u(uint32_t v, int l) {
  return (uint32_t)__builtin_amdgcn_readlane((int)v, l);
}

// offset of diagonal d; lo(d)=max(1,d-512)
__device__ __forceinline__ int offd(int d) {
  return (d <= 513) ? (((d - 2) * (d - 1)) >> 1)
                    : (NCELL - (((1025 - d) * (1026 - d)) >> 1));
}
__device__ __forceinline__ int dbase(int d) {
  const int lo = (d > 513) ? d - 512 : 1;
  return offd(d) - lo;
}
__device__ __forceinline__ int clampa(int a) {
  return a > (NCELL - 1) ? (NCELL - 1) : a;
}

// forward softmax-LSE cell (base-2 domain)
__device__ __forceinline__ void fcell(float& nv, uint32_t& pk, float dg, float up0,
                                      float lf0, float th, float A2) {
  float up = up0 + A2, lf = lf0 + A2;
  float mx = fmaxf(fmaxf(dg, up), lf);
  float ed = exp2f_(dg - mx), eu = exp2f_(up - mx), el = exp2f_(lf - mx);
  float s = ed + eu + el;
  nv = th + mx + log2f_(s);
  float rs = __builtin_amdgcn_rcpf(s);
  pk = pknorm16(ed * rs, eu * rs);
}
__device__ __forceinline__ float fcell_nopk(float dg, float up0, float lf0, float th, float A2) {
  float up = up0 + A2, lf = lf0 + A2;
  float mx = fmaxf(fmaxf(dg, up), lf);
  float s = exp2f_(dg - mx) + exp2f_(up - mx) + exp2f_(lf - mx);
  return th + mx + log2f_(s);
}

// ---------------------------------------------------------------------------
// K1: T[22][512] = W_embed @ W_proj + b_proj
// ---------------------------------------------------------------------------
__global__ void k_T(const float* __restrict__ We, const float* __restrict__ Wp,
                    const float* __restrict__ bp, float* __restrict__ T) {
  int a = blockIdx.x, c = threadIdx.x;
  __shared__ float e[512];
  e[c] = We[a * 512 + c];
  __syncthreads();
  float acc = bp[c];
#pragma unroll 8
  for (int k = 0; k < 512; ++k) acc = fmaf(e[k], Wp[k * 512 + c], acc);
  T[a * 512 + c] = acc;
}

// ---------------------------------------------------------------------------
// K2: G2 = (T T^T)/ln2 ; u,v gap LUTs
// ---------------------------------------------------------------------------
__global__ void k_G(const float* __restrict__ T, const float* __restrict__ Wg,
                    float* __restrict__ G, float* __restrict__ u, float* __restrict__ v) {
  __shared__ float Ts[22 * 516];
  for (int k = threadIdx.x; k < 22 * 512; k += 512) {
    int a = k >> 9, c = k & 511;
    Ts[a * 516 + c] = T[k];
  }
  __syncthreads();
  for (int idx = threadIdx.x; idx < 528; idx += 512) {
    float s = 0.f;
    if (idx < 484) {
      int a = idx / 22, a2 = idx - 22 * a;
      const float* pa = &Ts[a * 516];
      const float* pb = &Ts[a2 * 516];
      for (int c = 0; c < 512; ++c) s = fmaf(pa[c], pb[c], s);
      G[idx] = s * INVLN2;
    } else if (idx < 506) {
      int a = idx - 484;
      const float* pa = &Ts[a * 516];
      for (int c = 0; c < 512; ++c) s = fmaf(pa[c], Wg[c], s);
      u[a] = s;
    } else {
      int a = idx - 506;
      const float* pa = &Ts[a * 516];
      for (int c = 0; c < 512; ++c) s = fmaf(pa[c], Wg[512 + c], s);
      v[a] = s;
    }
  }
}

// ---------------------------------------------------------------------------
// K3: A2[b]
// ---------------------------------------------------------------------------
__global__ void k_A(const int* __restrict__ x, const int* __restrict__ y,
                    const float* __restrict__ u, const float* __restrict__ v,
                    const float* __restrict__ bg, float* __restrict__ A) {
  int b = blockIdx.x, t = threadIdx.x;
  const int* xb = x + b * 512;
  const int* yb = y + b * 512;
  float s = u[xb[t]] + u[xb[t + 256]] + v[yb[t]] + v[yb[t + 256]];
  for (int o = 32; o > 0; o >>= 1) s += __shfl_down(s, o, 64);
  __shared__ float w[4];
  if ((t & 63) == 0) w[t >> 6] = s;
  __syncthreads();
  if (t == 0) A[b] = ((w[0] + w[1] + w[2] + w[3]) * (1.0f / 512.0f) + bg[0]) * INVLN2;
}

// ---------------------------------------------------------------------------
// K4: register-resident KD-diagonal wavefront DP; DPP wave-shift rotates;
//     theta gathers software-pipelined one interval ahead.
// ---------------------------------------------------------------------------
__global__ __launch_bounds__(256) void k_nw(const int* __restrict__ x, const int* __restrict__ y,
                                            const float* __restrict__ G,
                                            const float* __restrict__ Aarr,
                                            uint32_t* __restrict__ po,
                                            float* __restrict__ ews) {
  const int b = blockIdx.x, tid = threadIdx.x;
  const int wave = tid >> 6, lane = tid & 63;
  __shared__ float Gl[484];
  __shared__ int ysL[512];
  __shared__ float Vc[2][516], Vp[2][516];

  const int* xb = x + b * 512;
  const int* yb = y + b * 512;
  ysL[tid] = yb[tid];
  ysL[tid + 256] = yb[tid + 256];
  for (int k = tid; k < 484; k += 256) Gl[k] = G[k];
  const float A2 = Aarr[b];

  const int r1 = 128 * wave + 2 * lane + 1, r2 = r1 + 1;
  const int xr1 = xb[r1 - 1] * 22, xr2 = xb[r2 - 1] * 22;
  const int Hrow = 128 * wave - (63 - lane);   // fwd halo row
  const int xrH = (Hrow >= 1) ? xb[Hrow - 1] * 22 : 0;
  const int HB = 128 * (wave + 1) + 1 + lane;  // bwd halo row
  const int HBc = HB <= 512 ? HB : 512;
  po += (size_t)b * NCELL;
  ews += (size_t)b * NCELL;
  __syncthreads();

  // ================= forward =================
  float th1[KD], th2[KD], thh[KD];
#pragma unroll
  for (int m = 0; m < KD; ++m) {  // prologue thetas for iv=0 (dn = 2+m)
    const int dn = 2 + m;
    unsigned j1 = (unsigned)(dn - r1 - 1);
    th1[m] = Gl[xr1 + ysL[j1 < 512u ? j1 : 0]];
    unsigned j2 = (unsigned)(dn - r2 - 1);
    th2[m] = Gl[xr2 + ysL[j2 < 512u ? j2 : 0]];
    unsigned jh = (unsigned)(dn - Hrow - 1);
    thh[m] = Gl[xrH + ysL[jh < 512u ? jh : 0]];
  }

  float a1 = NEGF, a2r = NEGF, b1v = NEGF, b2v = NEGF, ha = NEGF, hb = NEGF;
#pragma unroll 1
  for (int iv = 0; iv < NIV; ++iv) {
    const int d0 = 1 + KD * iv;
#pragma unroll
    for (int m = 0; m < KD; ++m) {
      const int dn = d0 + 1 + m;
      const int base = dbase(dn);
      const float wha = rdlane_f(ha, 63), whb = rdlane_f(hb, 63);
      float ra2 = dpp_shr1_f(a2r, wha);
      float rb2 = dpp_shr1_f(b2v, whb);
      float rha = dpp_shr1_f(ha, NEGF);
      float rhb = dpp_shr1_f(hb, NEGF);
      if (m == 0) {
        if (iv == 0 && tid == 0) rb2 = 0.0f;  // V[0,0] corner (dn==2)
      }
      float nv1, nv2;
      uint32_t pk1, pk2;
      fcell(nv1, pk1, rb2, ra2, a1, th1[m], A2);   // (r1): diag,up,left
      fcell(nv2, pk2, b1v, a1, a2r, th2[m], A2);   // (r2)
      float nh = fcell_nopk(rhb, rha, ha, thh[m], A2);
      const bool v1 = (unsigned)(dn - r1 - 1) < 512u;
      const bool v2 = (unsigned)(dn - r2 - 1) < 512u;
      const bool vh = (unsigned)(dn - Hrow - 1) < 512u;
      nv1 = v1 ? nv1 : NEGF;
      nv2 = v2 ? nv2 : NEGF;
      nh = (Hrow >= 1 && vh) ? nh : NEGF;
      if (v1) po[base + r1] = pk1;
      if (v2) po[base + r2] = pk2;
      b1v = a1; b2v = a2r; a1 = nv1; a2r = nv2; hb = ha; ha = nh;
      // refill theta slot m for interval iv+1 (hidden under remaining steps)
      {
        const int dnn = dn + KD;
        unsigned j1 = (unsigned)(dnn - r1 - 1);
        th1[m] = Gl[xr1 + ysL[j1 < 512u ? j1 : 0]];
        unsigned j2 = (unsigned)(dnn - r2 - 1);
        th2[m] = Gl[xr2 + ysL[j2 < 512u ? j2 : 0]];
        unsigned jh = (unsigned)(dnn - Hrow - 1);
        thh[m] = Gl[xrH + ysL[jh < 512u ? jh : 0]];
      }
    }
    // interval exchange (double-buffered)
    const int wb = iv & 1;
    Vc[wb][r1] = a1; Vc[wb][r2] = a2r;
    Vp[wb][r1] = b1v; Vp[wb][r2] = b2v;
    BAR();
    const int Hc = Hrow >= 1 ? Hrow : 1;
    const float hva = Vc[wb][Hc], hvb = Vp[wb][Hc];
    ha = (Hrow >= 1) ? hva : NEGF;
    hb = (Hrow >= 1) ? hvb : NEGF;
  }

  // ================= transition =================
  asm volatile("s_waitcnt vmcnt(0)" ::: "memory");
  __threadfence_block();
  __syncthreads();

  // ================= backward =================
  const float inv16 = 1.0f / 65535.0f;
  float e1a = 0.f, e1b = 0.f, e2a = 0.f, e2b = 0.f, hc = 0.f, hd = 0.f;
  if (wave == 3 && lane == 63) {
    e1b = 1.0f;  // E(512,512) on diag 1024
    ews[NCELL - 1] = 1.0f;
  }
#pragma unroll 1
  for (int iv = 0; iv < NIV; ++iv) {
    const int t0 = 1023 - KD * iv;
    uint32_t q1[KD + 1], q2[KD + 1], qh[KD + 1];
#pragma unroll
    for (int k = 0; k <= KD; ++k) {
      const int d = t0 + 2 - k;
      const int base = dbase(d);
      q1[k] = po[clampa(base + r1)];
      q2[k] = po[clampa(base + r2)];
      qh[k] = po[clampa(base + HBc)];
    }
#pragma unroll
    for (int m = 0; m < KD; ++m) {
      const int t = t0 - m;
      const int base = dbase(t);
      const float whc = rdlane_f(hc, 0), whd = rdlane_f(hd, 0);
      const uint32_t wqm = rdlane_u(qh[m], 0), wqm1 = rdlane_u(qh[m + 1], 0);
      float rc1 = dpp_shl1_f(e1a, whc);
      float rd1 = dpp_shl1_f(e2a, whd);
      uint32_t rQ = dpp_shl1_u(q1[m], wqm);
      uint32_t rP = dpp_shl1_u(q1[m + 1], wqm1);
      uint32_t rQh = dpp_shl1_u(qh[m], 0u);
      uint32_t rPh = dpp_shl1_u(qh[m + 1], 0u);
      float rhc = dpp_shl1_f(hc, 0.f);
      float rhd = dpp_shl1_f(hd, 0.f);
      // ---- cell (r1, j1=t-r1) ----
      const bool vd1 = (unsigned)(t - r1 - 1) < 512u;
      const bool rt1 = (unsigned)(t - r1) < 512u;
      float pd1 = (float)(q2[m] & 0xffffu) * inv16;
      float pu1 = (float)(q2[m + 1] >> 16) * inv16;
      float pl1 = 1.0f - (float)(q1[m + 1] & 0xffffu) * inv16
                       - (float)(q1[m + 1] >> 16) * inv16;
      float n1 = e1b * pu1 + (rt1 ? (e2b * pd1 + e1a * pl1) : 0.0f);
      n1 = vd1 ? n1 : 0.0f;
      if (vd1) ews[base + r1] = n1;
      // ---- cell (r2, j2=t-r2) ----
      const bool vd2 = (unsigned)(t - r2 - 1) < 512u;
      const bool rt2 = (unsigned)(t - r2) < 512u;
      const bool dn2 = r2 < 512;
      float pd2 = (float)(rQ & 0xffffu) * inv16;
      float pu2 = (float)(rP >> 16) * inv16;
      float pl2 = 1.0f - (float)(q2[m + 1] & 0xffffu) * inv16
                       - (float)(q2[m + 1] >> 16) * inv16;
      float n2 = ((dn2 && rt2) ? rd1 * pd2 : 0.0f) + (dn2 ? rc1 * pu2 : 0.0f)
               + (rt2 ? e1b * pl2 : 0.0f);
      n2 = vd2 ? n2 : 0.0f;
      if (vd2) ews[base + r2] = n2;
      // ---- halo (HB) ----
      const bool vdh = (unsigned)(t - HB - 1) < 512u;
      const bool rth = (unsigned)(t - HB) < 512u;
      const bool dnh = HB < 512;
      float pdh = (float)(rQh & 0xffffu) * inv16;
      float puh = (float)(rPh >> 16) * inv16;
      float plh = 1.0f - (float)(qh[m + 1] & 0xffffu) * inv16
                       - (float)(qh[m + 1] >> 16) * inv16;
      float nh = ((dnh && rth) ? rhd * pdh : 0.0f) + (dnh ? rhc * puh : 0.0f)
               + (rth ? hc * plh : 0.0f);
      nh = (HB <= 512 && vdh) ? nh : 0.0f;
      e2a = e1a; e2b = e1b; e1a = n1; e1b = n2; hd = hc; hc = nh;
    }
    const int wb = iv & 1;
    Vc[wb][r1] = e1a; Vc[wb][r2] = e1b;
    Vp[wb][r1] = e2a; Vp[wb][r2] = e2b;
    BAR();
    const float hea = Vc[wb][HBc], heb = Vp[wb][HBc];
    hc = (HB <= 512) ? hea : 0.0f;
    hd = (HB <= 512) ? heb : 0.0f;
  }
}

// ---------------------------------------------------------------------------
// K5: transpose diag-major E (ws) -> row-major out. 64x64 cell tiles.
// ---------------------------------------------------------------------------
__global__ __launch_bounds__(256) void k_tr(const float* __restrict__ ews, float* __restrict__ out) {
  const int blk = blockIdx.x;
  const int b = blk >> 6, ti = (blk >> 3) & 7, tj = blk & 7;
  const float* src = ews + (size_t)b * NCELL;
  float* dst = out + (size_t)b * NCELL;
  __shared__ float tile[64][68];
  const int i0 = ti * 64, j0 = tj * 64;
  const int t = threadIdx.x;
  const int sub = t >> 6, lane = t & 63;
  for (int k = sub; k < 127; k += 4) {
    const int d = i0 + j0 + 2 + k;
    const int ilo_t = max(i0 + 1, d - (j0 + 64));
    const int ihi_t = min(i0 + 64, d - (j0 + 1));
    const int i = ilo_t + lane;
    if (i <= ihi_t) {
      const int lo = (d > 513) ? d - 512 : 1;
      tile[i - 1 - i0][d - i - 1 - j0] = src[offd(d) - lo + i];
    }
  }
  __syncthreads();
  const int r = t >> 2, q = (t & 3) * 16;
  float4* drow = (float4*)&dst[(size_t)(i0 + r) * 512 + j0 + q];
  const float* srow = &tile[r][q];
  drow[0] = *(const float4*)&srow[0];
  drow[1] = *(const float4*)&srow[4];
  drow[2] = *(const float4*)&srow[8];
  drow[3] = *(const float4*)&srow[12];
}

// ---------------------------------------------------------------------------
extern "C" void kernel_launch(void* const* d_in, const int* in_sizes, int n_in,
                              void* d_out, int out_size, void* d_ws, size_t ws_size,
                              hipStream_t stream) {
  const int* x = (const int*)d_in[0];
  const int* y = (const int*)d_in[1];
  const float* We = (const float*)d_in[2];
  const float* Wp = (const float*)d_in[3];
  const float* bp = (const float*)d_in[4];
  const float* Wg = (const float*)d_in[5];
  const float* bg = (const float*)d_in[6];
  float* out = (float*)d_out;

  float* ws = (float*)d_ws;
  float* T = ws;              // 22*512 floats
  float* G = ws + 11264;      // 484
  float* u = G + 484;         // 22
  float* v = u + 22;          // 22
  float* A = v + 22;          // 16
  float* ews = (float*)((char*)d_ws + (1 << 20));  // 16 MiB diag-major E

  k_T<<<22, 512, 0, stream>>>(We, Wp, bp, T);
  k_G<<<1, 512, 0, stream>>>(T, Wg, G, u, v);
  k_A<<<16, 256, 0, stream>>>(x, y, u, v, bg, A);
  k_nw<<<16, 256, 0, stream>>>(x, y, G, A, (uint32_t*)d_out, ews);
  k_tr<<<16 * 64, 256, 0, stream>>>(ews, out);
}

// Round 7
// 584.246 us; speedup vs baseline: 1.3371x; 1.3371x over previous
//
#include <hip/hip_runtime.h>
#include <stdint.h>

#define NEGF (-1.0e8f)
#define NCELL (512 * 512)
#define INVLN2 1.4426950408889634f
#define NIV 71  // intervals: ceil((1023 + 7*16 + 1)/16)

// raw barrier: LDS ordering only (never drains vmcnt -> global ops stay in flight)
#define BAR() asm volatile("s_waitcnt lgkmcnt(0)\n\ts_barrier" ::: "memory")

__device__ __forceinline__ float exp2f_(float x) {
#if __has_builtin(__builtin_amdgcn_exp2f)
  return __builtin_amdgcn_exp2f(x);
#else
  return exp2f(x);
#endif
}
__device__ __forceinline__ float log2f_(float x) {
#if __has_builtin(__builtin_amdgcn_logf)
  return __builtin_amdgcn_logf(x);
#else
  return log2f(x);
#endif
}
__device__ __forceinline__ uint32_t pknorm16(float a, float b) {
#if __has_builtin(__builtin_amdgcn_cvt_pknorm_u16)
  typedef unsigned short u2v __attribute__((ext_vector_type(2)));
  union { u2v v; uint32_t u; } cv;
  cv.v = __builtin_amdgcn_cvt_pknorm_u16(a, b);
  return cv.u;
#else
  uint32_t pa = (uint32_t)(a * 65535.0f + 0.5f);
  uint32_t pb = (uint32_t)(b * 65535.0f + 0.5f);
  return pa | (pb << 16);
#endif
}

// DPP wave shifts: 0x138 wave_shr:1 (lane l <- l-1, lane0 <- old), 0x130 wave_shl:1 (lane l <- l+1, lane63 <- old)
__device__ __forceinline__ float dpp_shr1_f(float src, float old0) {
  return __int_as_float(__builtin_amdgcn_update_dpp(
      __float_as_int(old0), __float_as_int(src), 0x138, 0xF, 0xF, false));
}
__device__ __forceinline__ float dpp_shl1_f(float src, float old63) {
  return __int_as_float(__builtin_amdgcn_update_dpp(
      __float_as_int(old63), __float_as_int(src), 0x130, 0xF, 0xF, false));
}
__device__ __forceinline__ uint32_t dpp_shl1_u(uint32_t src, uint32_t old63) {
  return (uint32_t)__builtin_amdgcn_update_dpp((int)old63, (int)src, 0x130, 0xF, 0xF, false);
}

// offset of diagonal d; lo(d)=max(1,d-512). Valid-positive for all int d used here.
__device__ __forceinline__ int offd(int d) {
  return (d <= 513) ? (((d - 2) * (d - 1)) >> 1)
                    : (NCELL - (((1025 - d) * (1026 - d)) >> 1));
}
__device__ __forceinline__ int dbase(int d) {
  const int lo = (d > 513) ? d - 512 : 1;
  return offd(d) - lo;
}
__device__ __forceinline__ int clampa(int a) {
  return a > (NCELL - 1) ? (NCELL - 1) : (a < 0 ? 0 : a);
}

// forward softmax-LSE cell (base-2 domain)
__device__ __forceinline__ void fcell(float& nv, uint32_t& pk, float dg, float up0,
                                      float lf0, float th, float A2) {
  float up = up0 + A2, lf = lf0 + A2;
  float mx = fmaxf(fmaxf(dg, up), lf);
  float ed = exp2f_(dg - mx), eu = exp2f_(up - mx), el = exp2f_(lf - mx);
  float s = ed + eu + el;
  nv = th + mx + log2f_(s);
  float rs = __builtin_amdgcn_rcpf(s);
  pk = pknorm16(ed * rs, eu * rs);
}

// ---------------------------------------------------------------------------
// K1: T[22][512] = W_embed @ W_proj + b_proj
// ---------------------------------------------------------------------------
__global__ void k_T(const float* __restrict__ We, const float* __restrict__ Wp,
                    const float* __restrict__ bp, float* __restrict__ T) {
  int a = blockIdx.x, c = threadIdx.x;
  __shared__ float e[512];
  e[c] = We[a * 512 + c];
  __syncthreads();
  float acc = bp[c];
#pragma unroll 8
  for (int k = 0; k < 512; ++k) acc = fmaf(e[k], Wp[k * 512 + c], acc);
  T[a * 512 + c] = acc;
}

// ---------------------------------------------------------------------------
// K2: G2[a][a2] (padded 22x32) = (T T^T)/ln2 ; u,v gap LUTs
// ---------------------------------------------------------------------------
__global__ void k_G(const float* __restrict__ T, const float* __restrict__ Wg,
                    float* __restrict__ G, float* __restrict__ u, float* __restrict__ v) {
  __shared__ float Ts[22 * 516];
  for (int k = threadIdx.x; k < 22 * 512; k += 512) {
    int a = k >> 9, c = k & 511;
    Ts[a * 516 + c] = T[k];
  }
  __syncthreads();
  for (int idx = threadIdx.x; idx < 528; idx += 512) {
    float s = 0.f;
    if (idx < 484) {
      int a = idx / 22, a2 = idx - 22 * a;
      const float* pa = &Ts[a * 516];
      const float* pb = &Ts[a2 * 516];
      for (int c = 0; c < 512; ++c) s = fmaf(pa[c], pb[c], s);
      G[a * 32 + a2] = s * INVLN2;  // padded row stride 32
    } else if (idx < 506) {
      int a = idx - 484;
      const float* pa = &Ts[a * 516];
      for (int c = 0; c < 512; ++c) s = fmaf(pa[c], Wg[c], s);
      u[a] = s;
    } else {
      int a = idx - 506;
      const float* pa = &Ts[a * 516];
      for (int c = 0; c < 512; ++c) s = fmaf(pa[c], Wg[512 + c], s);
      v[a] = s;
    }
  }
}

// ---------------------------------------------------------------------------
// K3: A2[b]
// ---------------------------------------------------------------------------
__global__ void k_A(const int* __restrict__ x, const int* __restrict__ y,
                    const float* __restrict__ u, const float* __restrict__ v,
                    const float* __restrict__ bg, float* __restrict__ A) {
  int b = blockIdx.x, t = threadIdx.x;
  const int* xb = x + b * 512;
  const int* yb = y + b * 512;
  float s = u[xb[t]] + u[xb[t + 256]] + v[yb[t]] + v[yb[t + 256]];
  for (int o = 32; o > 0; o >>= 1) s += __shfl_down(s, o, 64);
  __shared__ float w[4];
  if ((t & 63) == 0) w[t >> 6] = s;
  __syncthreads();
  if (t == 0) A[b] = ((w[0] + w[1] + w[2] + w[3]) * (1.0f / 512.0f) + bg[0]) * INVLN2;
}

// ---------------------------------------------------------------------------
// K4: skewed 8-wave pipeline DP. 512 threads, 1 row/lane (r=64w+lane+1).
//     Wave w lags its upstream neighbor by 16 diagonals; boundary values flow
//     through LDS rings (depth 64). All interval state in named scalars.
// ---------------------------------------------------------------------------
__global__ __launch_bounds__(512) void k_nw(const int* __restrict__ x, const int* __restrict__ y,
                                            const float* __restrict__ G,
                                            const float* __restrict__ Aarr,
                                            uint32_t* __restrict__ po,
                                            float* __restrict__ ews) {
  const int b = blockIdx.x, tid = threadIdx.x;
  const int w = tid >> 6, lane = tid & 63;
  __shared__ float Gl[704];
  __shared__ int ysL[512];
  __shared__ float Vring[7][64];
  __shared__ float Ering[7][64];
  __shared__ uint32_t Pring[7][64];

  const int* xb = x + b * 512;
  const int* yb = y + b * 512;
  ysL[tid] = yb[tid];
  Gl[tid] = G[tid];
  if (tid + 512 < 704) Gl[tid + 512] = G[tid + 512];
  const float A2 = Aarr[b];
  const int r = 64 * w + lane + 1;
  const int xr = xb[r - 1] << 5;
  const bool w0 = (w == 0), w7 = (w == 7), wgt0 = (w > 0), wlt7 = (w < 7);
  const bool lane0 = (lane == 0), lane63 = (lane == 63);
  const bool rless = (r < 512);
  const int wm1 = wgt0 ? w - 1 : 0;
  const int wc = wlt7 ? w : 6;
  po += (size_t)b * NCELL;
  ews += (size_t)b * NCELL;
  __syncthreads();

  // ================= forward =================
  float th0, th1, th2, th3, th4, th5, th6, th7, th8, th9, th10, th11, th12, th13, th14, th15;
#define PROTH(m) { unsigned jq = (unsigned)((2 - 16 * w + (m)) - r - 1); \
                   th##m = Gl[xr + ysL[jq < 512u ? jq : 0]]; }
  PROTH(0) PROTH(1) PROTH(2) PROTH(3) PROTH(4) PROTH(5) PROTH(6) PROTH(7)
  PROTH(8) PROTH(9) PROTH(10) PROTH(11) PROTH(12) PROTH(13) PROTH(14) PROTH(15)

  float va = NEGF, vb = NEGF;
#pragma unroll 1
  for (int iv = 0; iv < NIV; ++iv) {
    const int dn0 = 2 - 16 * w + 16 * iv;
    const float* Vr = &Vring[wm1][0];
    float rv0, rv1, rv2, rv3, rv4, rv5, rv6, rv7, rv8, rv9, rv10, rv11, rv12, rv13, rv14, rv15, rv16;
#define PFV(k) rv##k = Vr[(dn0 - 2 + (k)) & 63];
    PFV(0) PFV(1) PFV(2) PFV(3) PFV(4) PFV(5) PFV(6) PFV(7) PFV(8)
    PFV(9) PFV(10) PFV(11) PFV(12) PFV(13) PFV(14) PFV(15) PFV(16)

#define FSTEP(m, RA, RB) { \
    const int dn = dn0 + (m); \
    const int base = dbase(dn); \
    float rup = dpp_shr1_f(va, w0 ? NEGF : (RB)); \
    float rdg = dpp_shr1_f(vb, w0 ? NEGF : (RA)); \
    if (w0 && lane0 && dn == 2) rdg = 0.0f; \
    float nv; uint32_t pk; \
    fcell(nv, pk, rdg, rup, va, th##m, A2); \
    const bool vv = (unsigned)(dn - r - 1) < 512u; \
    nv = vv ? nv : NEGF; \
    if (vv) po[base + r] = pk; \
    vb = va; va = nv; \
    if (wlt7 && lane63) Vring[w][dn & 63] = nv; \
    { unsigned jq = (unsigned)(dn + 16 - r - 1); \
      th##m = Gl[xr + ysL[jq < 512u ? jq : 0]]; } \
  }
    FSTEP(0, rv0, rv1) FSTEP(1, rv1, rv2) FSTEP(2, rv2, rv3) FSTEP(3, rv3, rv4)
    FSTEP(4, rv4, rv5) FSTEP(5, rv5, rv6) FSTEP(6, rv6, rv7) FSTEP(7, rv7, rv8)
    FSTEP(8, rv8, rv9) FSTEP(9, rv9, rv10) FSTEP(10, rv10, rv11) FSTEP(11, rv11, rv12)
    FSTEP(12, rv12, rv13) FSTEP(13, rv13, rv14) FSTEP(14, rv14, rv15) FSTEP(15, rv15, rv16)
    BAR();
  }

  // ================= transition: drain p stores once =================
  asm volatile("s_waitcnt vmcnt(0)" ::: "memory");
  __threadfence_block();
  __syncthreads();

  // ================= backward =================
  const float inv16 = 1.0f / 65535.0f;
  float ea = (w7 && lane63) ? 1.0f : 0.0f, eb = 0.0f;
  if (w7 && lane63) ews[NCELL - 1] = 1.0f;  // E(512,512) seed (diag 1024)
  float* ErW = &Ering[wm1][0];
  uint32_t* PrW = &Pring[wm1][0];

  uint32_t q0, q1, q2, q3, q4, q5, q6, q7, q8, q9, q10, q11, q12, q13, q14, q15, q16;
  uint32_t qn0, qn1, qn2, qn3, qn4, qn5, qn6, qn7, qn8, qn9, qn10, qn11, qn12, qn13, qn14, qn15, qn16;
  {
    const int t0p = 1135 - 16 * w;
#define QLD0(k) q##k = po[clampa(dbase(t0p + 2 - (k)) + r)];
    QLD0(0) QLD0(1) QLD0(2) QLD0(3) QLD0(4) QLD0(5) QLD0(6) QLD0(7) QLD0(8)
    QLD0(9) QLD0(10) QLD0(11) QLD0(12) QLD0(13) QLD0(14) QLD0(15) QLD0(16)
  }

#pragma unroll 1
  for (int iv = 0; iv < NIV; ++iv) {
    const int t0 = 1135 - 16 * w - 16 * iv;
    const float* Er = &Ering[wc][0];
    const uint32_t* Pr = &Pring[wc][0];
    float rE0, rE1, rE2, rE3, rE4, rE5, rE6, rE7, rE8, rE9, rE10, rE11, rE12, rE13, rE14, rE15, rE16;
    uint32_t rP0, rP1, rP2, rP3, rP4, rP5, rP6, rP7, rP8, rP9, rP10, rP11, rP12, rP13, rP14, rP15, rP16;
#define PFB(k) { const int dd = (t0 + 2 - (k)) & 63; rE##k = Er[dd]; rP##k = Pr[dd]; }
    PFB(0) PFB(1) PFB(2) PFB(3) PFB(4) PFB(5) PFB(6) PFB(7) PFB(8)
    PFB(9) PFB(10) PFB(11) PFB(12) PFB(13) PFB(14) PFB(15) PFB(16)
    // issue next-interval p loads (stay in flight across BAR)
    {
      const int t0n = t0 - 16;
#define QLDN(k) qn##k = po[clampa(dbase(t0n + 2 - (k)) + r)];
      QLDN(0) QLDN(1) QLDN(2) QLDN(3) QLDN(4) QLDN(5) QLDN(6) QLDN(7) QLDN(8)
      QLDN(9) QLDN(10) QLDN(11) QLDN(12) QLDN(13) QLDN(14) QLDN(15) QLDN(16)
    }

#define BSTEP(m, Qm, Qm1, REm, REm1, RPm, RPm1) { \
    const int t = t0 - (m); \
    const int base = dbase(t); \
    const float rea = dpp_shl1_f(ea, w7 ? 0.0f : (REm1)); \
    const float reb = dpp_shl1_f(eb, w7 ? 0.0f : (REm)); \
    const uint32_t rq2 = dpp_shl1_u((Qm), w7 ? 0u : (RPm)); \
    const uint32_t rq1 = dpp_shl1_u((Qm1), w7 ? 0u : (RPm1)); \
    const bool vd = (unsigned)(t - r - 1) < 512u; \
    const bool rt = (unsigned)(t - r) < 512u; \
    const float pd = (float)(rq2 & 0xffffu) * inv16; \
    const float pu = (float)(rq1 >> 16) * inv16; \
    const float pl = 1.0f - (float)((Qm1) & 0xffffu) * inv16 - (float)((Qm1) >> 16) * inv16; \
    float n = (rless ? rea * pu : 0.0f) + ((rless && rt) ? reb * pd : 0.0f) + (rt ? ea * pl : 0.0f); \
    n = vd ? n : 0.0f; \
    if (vd) ews[base + r] = n; \
    eb = ea; ea = n; \
    if (wgt0 && lane0) ErW[t & 63] = n; \
  }
    BSTEP(0, q0, q1, rE0, rE1, rP0, rP1) BSTEP(1, q1, q2, rE1, rE2, rP1, rP2)
    BSTEP(2, q2, q3, rE2, rE3, rP2, rP3) BSTEP(3, q3, q4, rE3, rE4, rP3, rP4)
    BSTEP(4, q4, q5, rE4, rE5, rP4, rP5) BSTEP(5, q5, q6, rE5, rE6, rP5, rP6)
    BSTEP(6, q6, q7, rE6, rE7, rP6, rP7) BSTEP(7, q7, q8, rE7, rE8, rP7, rP8)
    BSTEP(8, q8, q9, rE8, rE9, rP8, rP9) BSTEP(9, q9, q10, rE9, rE10, rP9, rP10)
    BSTEP(10, q10, q11, rE10, rE11, rP10, rP11) BSTEP(11, q11, q12, rE11, rE12, rP11, rP12)
    BSTEP(12, q12, q13, rE12, rE13, rP12, rP13) BSTEP(13, q13, q14, rE13, rE14, rP13, rP14)
    BSTEP(14, q14, q15, rE14, rE15, rP14, rP15) BSTEP(15, q15, q16, rE15, rE16, rP15, rP16)

    // publish own p-packs for downstream reader's next interval
    if (wgt0 && lane0) {
#define PWR(k) PrW[(t0 + 2 - (k)) & 63] = q##k;
      PWR(0) PWR(1) PWR(2) PWR(3) PWR(4) PWR(5) PWR(6) PWR(7) PWR(8)
      PWR(9) PWR(10) PWR(11) PWR(12) PWR(13) PWR(14) PWR(15) PWR(16)
    }
    // roll pipelined q
#define QMV(k) q##k = qn##k;
    QMV(0) QMV(1) QMV(2) QMV(3) QMV(4) QMV(5) QMV(6) QMV(7) QMV(8)
    QMV(9) QMV(10) QMV(11) QMV(12) QMV(13) QMV(14) QMV(15) QMV(16)
    BAR();
  }
}

// ---------------------------------------------------------------------------
// K5: transpose diag-major E (ws) -> row-major out. 64x64 cell tiles.
// ---------------------------------------------------------------------------
__global__ __launch_bounds__(256) void k_tr(const float* __restrict__ ews, float* __restrict__ out) {
  const int blk = blockIdx.x;
  const int b = blk >> 6, ti = (blk >> 3) & 7, tj = blk & 7;
  const float* src = ews + (size_t)b * NCELL;
  float* dst = out + (size_t)b * NCELL;
  __shared__ float tile[64][68];
  const int i0 = ti * 64, j0 = tj * 64;
  const int t = threadIdx.x;
  const int sub = t >> 6, lane = t & 63;
  for (int k = sub; k < 127; k += 4) {
    const int d = i0 + j0 + 2 + k;
    const int ilo_t = max(i0 + 1, d - (j0 + 64));
    const int ihi_t = min(i0 + 64, d - (j0 + 1));
    const int i = ilo_t + lane;
    if (i <= ihi_t) {
      const int lo = (d > 513) ? d - 512 : 1;
      tile[i - 1 - i0][d - i - 1 - j0] = src[offd(d) - lo + i];
    }
  }
  __syncthreads();
  const int rr = t >> 2, q = (t & 3) * 16;
  float4* drow = (float4*)&dst[(size_t)(i0 + rr) * 512 + j0 + q];
  const float* srow = &tile[rr][q];
  drow[0] = *(const float4*)&srow[0];
  drow[1] = *(const float4*)&srow[4];
  drow[2] = *(const float4*)&srow[8];
  drow[3] = *(const float4*)&srow[12];
}

// ---------------------------------------------------------------------------
extern "C" void kernel_launch(void* const* d_in, const int* in_sizes, int n_in,
                              void* d_out, int out_size, void* d_ws, size_t ws_size,
                              hipStream_t stream) {
  const int* x = (const int*)d_in[0];
  const int* y = (const int*)d_in[1];
  const float* We = (const float*)d_in[2];
  const float* Wp = (const float*)d_in[3];
  const float* bp = (const float*)d_in[4];
  const float* Wg = (const float*)d_in[5];
  const float* bg = (const float*)d_in[6];
  float* out = (float*)d_out;

  float* ws = (float*)d_ws;
  float* T = ws;              // 22*512 floats
  float* G = ws + 11264;      // 704 (22x32 padded)
  float* u = G + 704;         // 22
  float* v = u + 22;          // 22
  float* A = v + 22;          // 16
  float* ews = (float*)((char*)d_ws + (1 << 20));  // 16 MiB diag-major E

  k_T<<<22, 512, 0, stream>>>(We, Wp, bp, T);
  k_G<<<1, 512, 0, stream>>>(T, Wg, G, u, v);
  k_A<<<16, 256, 0, stream>>>(x, y, u, v, bg, A);
  k_nw<<<16, 512, 0, stream>>>(x, y, G, A, (uint32_t*)d_out, ews);
  k_tr<<<16 * 64, 256, 0, stream>>>(ews, out);
}

// Round 9
// 536.084 us; speedup vs baseline: 1.4572x; 1.0898x over previous
//
#include <hip/hip_runtime.h>
#include <stdint.h>

#define NEGF (-1.0e8f)
#define NCELL (512 * 512)
#define INVLN2 1.4426950408889634f
#define NIV 71  // intervals of 16 diagonals; skew 16/wave

// raw barrier: LDS ordering only (never drains vmcnt -> global ops stay in flight)
#define BAR() asm volatile("s_waitcnt lgkmcnt(0)\n\ts_barrier" ::: "memory")

__device__ __forceinline__ float exp2f_(float x) {
#if __has_builtin(__builtin_amdgcn_exp2f)
  return __builtin_amdgcn_exp2f(x);
#else
  return exp2f(x);
#endif
}
__device__ __forceinline__ float log2f_(float x) {
#if __has_builtin(__builtin_amdgcn_logf)
  return __builtin_amdgcn_logf(x);
#else
  return log2f(x);
#endif
}
__device__ __forceinline__ uint32_t pknorm16(float a, float b) {
#if __has_builtin(__builtin_amdgcn_cvt_pknorm_u16)
  typedef unsigned short u2v __attribute__((ext_vector_type(2)));
  union { u2v v; uint32_t u; } cv;
  cv.v = __builtin_amdgcn_cvt_pknorm_u16(a, b);
  return cv.u;
#else
  uint32_t pa = (uint32_t)(a * 65535.0f + 0.5f);
  uint32_t pb = (uint32_t)(b * 65535.0f + 0.5f);
  return pa | (pb << 16);
#endif
}

// DPP wave shifts: 0x138 wave_shr:1 (lane l <- l-1, lane0 <- old), 0x130 wave_shl:1 (lane l <- l+1, lane63 <- old)
__device__ __forceinline__ float dpp_shr1_f(float src, float old0) {
  return __int_as_float(__builtin_amdgcn_update_dpp(
      __float_as_int(old0), __float_as_int(src), 0x138, 0xF, 0xF, false));
}
__device__ __forceinline__ float dpp_shl1_f(float src, float old63) {
  return __int_as_float(__builtin_amdgcn_update_dpp(
      __float_as_int(old63), __float_as_int(src), 0x130, 0xF, 0xF, false));
}
__device__ __forceinline__ uint32_t dpp_shl1_u(uint32_t src, uint32_t old63) {
  return (uint32_t)__builtin_amdgcn_update_dpp((int)old63, (int)src, 0x130, 0xF, 0xF, false);
}

// offset of diagonal d; lo(d)=max(1,d-512)
__device__ __forceinline__ int offd(int d) {
  return (d <= 513) ? (((d - 2) * (d - 1)) >> 1)
                    : (NCELL - (((1025 - d) * (1026 - d)) >> 1));
}
__device__ __forceinline__ int dbase(int d) {
  const int lo = (d > 513) ? d - 512 : 1;
  return offd(d) - lo;
}

// forward softmax-LSE cell (base-2 domain)
__device__ __forceinline__ void fcell(float& nv, uint32_t& pk, float dg, float up0,
                                      float lf0, float th, float A2) {
  float up = up0 + A2, lf = lf0 + A2;
  float mx = fmaxf(fmaxf(dg, up), lf);
  float ed = exp2f_(dg - mx), eu = exp2f_(up - mx), el = exp2f_(lf - mx);
  float s = ed + eu + el;
  nv = th + mx + log2f_(s);
  float rs = __builtin_amdgcn_rcpf(s);
  pk = pknorm16(ed * rs, eu * rs);
}

// ---------------------------------------------------------------------------
// K1: T[22][512] = W_embed @ W_proj + b_proj
// ---------------------------------------------------------------------------
__global__ void k_T(const float* __restrict__ We, const float* __restrict__ Wp,
                    const float* __restrict__ bp, float* __restrict__ T) {
  int a = blockIdx.x, c = threadIdx.x;
  __shared__ float e[512];
  e[c] = We[a * 512 + c];
  __syncthreads();
  float acc = bp[c];
#pragma unroll 8
  for (int k = 0; k < 512; ++k) acc = fmaf(e[k], Wp[k * 512 + c], acc);
  T[a * 512 + c] = acc;
}

// ---------------------------------------------------------------------------
// K2: G2[a][a2] (stride 37 for LDS bank spread) = (T T^T)/ln2 ; u,v gap LUTs
// ---------------------------------------------------------------------------
__global__ void k_G(const float* __restrict__ T, const float* __restrict__ Wg,
                    float* __restrict__ G, float* __restrict__ u, float* __restrict__ v) {
  __shared__ float Ts[22 * 516];
  for (int k = threadIdx.x; k < 22 * 512; k += 512) {
    int a = k >> 9, c = k & 511;
    Ts[a * 516 + c] = T[k];
  }
  __syncthreads();
  for (int idx = threadIdx.x; idx < 528; idx += 512) {
    float s = 0.f;
    if (idx < 484) {
      int a = idx / 22, a2 = idx - 22 * a;
      const float* pa = &Ts[a * 516];
      const float* pb = &Ts[a2 * 516];
      for (int c = 0; c < 512; ++c) s = fmaf(pa[c], pb[c], s);
      G[a * 37 + a2] = s * INVLN2;  // padded row stride 37
    } else if (idx < 506) {
      int a = idx - 484;
      const float* pa = &Ts[a * 516];
      for (int c = 0; c < 512; ++c) s = fmaf(pa[c], Wg[c], s);
      u[a] = s;
    } else {
      int a = idx - 506;
      const float* pa = &Ts[a * 516];
      for (int c = 0; c < 512; ++c) s = fmaf(pa[c], Wg[512 + c], s);
      v[a] = s;
    }
  }
}

// ---------------------------------------------------------------------------
// K3: A2[b]
// ---------------------------------------------------------------------------
__global__ void k_A(const int* __restrict__ x, const int* __restrict__ y,
                    const float* __restrict__ u, const float* __restrict__ v,
                    const float* __restrict__ bg, float* __restrict__ A) {
  int b = blockIdx.x, t = threadIdx.x;
  const int* xb = x + b * 512;
  const int* yb = y + b * 512;
  float s = u[xb[t]] + u[xb[t + 256]] + v[yb[t]] + v[yb[t + 256]];
  for (int o = 32; o > 0; o >>= 1) s += __shfl_down(s, o, 64);
  __shared__ float w[4];
  if ((t & 63) == 0) w[t >> 6] = s;
  __syncthreads();
  if (t == 0) A[b] = ((w[0] + w[1] + w[2] + w[3]) * (1.0f / 512.0f) + bg[0]) * INVLN2;
}

// ---------------------------------------------------------------------------
// K4: skewed 8-wave pipeline DP. 512 threads, 1 row/lane (r=64w+lane+1).
//     Consumer-indexed linear rings, carried DPP values, scalarized w.
// ---------------------------------------------------------------------------
__global__ __launch_bounds__(512) void k_nw(const int* __restrict__ x, const int* __restrict__ y,
                                            const float* __restrict__ G,
                                            const float* __restrict__ Aarr,
                                            uint32_t* __restrict__ po,
                                            float* __restrict__ ews) {
  const int tid = threadIdx.x;
  const int w = __builtin_amdgcn_readfirstlane(tid) >> 6;  // wave id, forced SGPR
  const int lane = tid & 63;
  __shared__ float Gl[814];       // 22 x 37
  __shared__ int ysPad[1856];     // ys values padded; index = dn-1-r + 640
  __shared__ float Vring[8][128];     // Vring[w] read by wave w (fwd); written by w-1
  __shared__ float Ering[8][128];     // Ering[w] read by wave w (bwd); written by w+1
  __shared__ uint32_t Pring[8][128];  // same indexing as Ering

  const int b = blockIdx.x;
  const int* xbp = x + b * 512;
  const int* ybp = y + b * 512;
  // ysPad: zero pads + values at [640, 1152)
  for (int k = tid; k < 640; k += 512) ysPad[k] = 0;
  for (int k = 1152 + tid; k < 1856; k += 512) ysPad[k] = 0;
  ysPad[640 + tid] = ybp[tid];
  for (int k = tid; k < 814; k += 512) Gl[k] = G[k];
  if (tid < 128) {
    Vring[0][tid] = NEGF;   // row-0 border: V(0,*) = -inf (corner patched in-step)
    Ering[7][tid] = 0.0f;   // row-513 border: E = 0
    Pring[7][tid] = 0u;     // row-513 border: p = 0
  }
  const float A2 = Aarr[b];
  const int r = 64 * w + lane + 1;
  const int xr = xbp[r - 1] * 37;
  const bool lane0 = (lane == 0), lane63 = (lane == 63);
  const bool wgt0 = (w > 0), wlt7 = (w < 7);
  const bool rless = (r < 512);
  po += (size_t)b * NCELL;
  ews += (size_t)b * NCELL;
  __syncthreads();

  // ================= forward =================
  float th0, th1, th2, th3, th4, th5, th6, th7, th8, th9, th10, th11, th12, th13, th14, th15;
#define PROTH(m) { const int ix = (2 - 16 * w + (m)) + 639 - r; th##m = Gl[xr + ysPad[ix]]; }
  PROTH(0) PROTH(1) PROTH(2) PROTH(3) PROTH(4) PROTH(5) PROTH(6) PROTH(7)
  PROTH(8) PROTH(9) PROTH(10) PROTH(11) PROTH(12) PROTH(13) PROTH(14) PROTH(15)

  float va = NEGF, rupP = NEGF;
#pragma unroll 1
  for (int iv = 0; iv < NIV; ++iv) {
    const int dn0 = 2 - 16 * w + 16 * iv;  // scalar (w scalar, iv uniform)
    const int sV = (dn0 - 1) & 63;
    const float* Vr2 = &Vring[w][sV];
    float rv1, rv2, rv3, rv4, rv5, rv6, rv7, rv8, rv9, rv10, rv11, rv12, rv13, rv14, rv15, rv16;
#define PFV(k) rv##k = Vr2[(k) - 1];
    PFV(1) PFV(2) PFV(3) PFV(4) PFV(5) PFV(6) PFV(7) PFV(8)
    PFV(9) PFV(10) PFV(11) PFV(12) PFV(13) PFV(14) PFV(15) PFV(16)

#define FSTEP(m, RVN) { \
    const int dn = dn0 + (m); \
    float rdg = rupP; \
    if ((m) == 0 && w == 0 && iv == 0) rdg = lane0 ? 0.0f : rdg; /* V[0,0]=0 corner */ \
    const float rup = dpp_shr1_f(va, (RVN)); \
    float nv; uint32_t pk; \
    fcell(nv, pk, rdg, rup, va, th##m, A2); \
    const bool vv = (unsigned)(dn - r - 1) < 512u; \
    nv = vv ? nv : NEGF; \
    if (vv) po[dbase(dn) + r] = pk; \
    if (wlt7 && lane63) { const int sl = dn & 63; Vring[w + 1][sl] = nv; Vring[w + 1][sl + 64] = nv; } \
    { const int ix = dn + 655 - r; th##m = Gl[xr + ysPad[ix]]; } \
    va = nv; rupP = rup; \
  }
    FSTEP(0, rv1) FSTEP(1, rv2) FSTEP(2, rv3) FSTEP(3, rv4)
    FSTEP(4, rv5) FSTEP(5, rv6) FSTEP(6, rv7) FSTEP(7, rv8)
    FSTEP(8, rv9) FSTEP(9, rv10) FSTEP(10, rv11) FSTEP(11, rv12)
    FSTEP(12, rv13) FSTEP(13, rv14) FSTEP(14, rv15) FSTEP(15, rv16)
    BAR();
  }

  // ================= transition: drain p stores once =================
  asm volatile("s_waitcnt vmcnt(0)" ::: "memory");
  __threadfence_block();
  __syncthreads();

  // ================= backward =================
  const float inv16 = 1.0f / 65535.0f;
  const bool w7 = (w == 7);
  float ea = (w7 && lane63) ? 1.0f : 0.0f;
  float reaP = 0.0f;
  uint32_t rqP = 0u;
  if (w7 && lane63) ews[NCELL - 1] = 1.0f;  // E(512,512) seed (diag 1024)

  uint32_t q0, q1, q2, q3, q4, q5, q6, q7, q8, q9, q10, q11, q12, q13, q14, q15, q16;
  uint32_t qn0, qn1, qn2, qn3, qn4, qn5, qn6, qn7, qn8, qn9, qn10, qn11, qn12, qn13, qn14, qn15, qn16;
  {
    const int t0p = 1135 - 16 * w;
#define QLD0(k) q##k = po[dbase(t0p + 2 - (k)) + r];
    QLD0(0) QLD0(1) QLD0(2) QLD0(3) QLD0(4) QLD0(5) QLD0(6) QLD0(7) QLD0(8)
    QLD0(9) QLD0(10) QLD0(11) QLD0(12) QLD0(13) QLD0(14) QLD0(15) QLD0(16)
  }

#pragma unroll 1
  for (int iv = 0; iv < NIV; ++iv) {
    const int t0 = 1135 - 16 * w - 16 * iv;  // scalar
    const int sE = (t0 - 14) & 63;
    const float* Er2 = &Ering[w][sE];
    const uint32_t* Pr2 = &Pring[w][sE];
    float rE1, rE2, rE3, rE4, rE5, rE6, rE7, rE8, rE9, rE10, rE11, rE12, rE13, rE14, rE15, rE16;
    uint32_t rP1, rP2, rP3, rP4, rP5, rP6, rP7, rP8, rP9, rP10, rP11, rP12, rP13, rP14, rP15, rP16;
#define PFB(k) rE##k = Er2[16 - (k)]; rP##k = Pr2[16 - (k)];
    PFB(1) PFB(2) PFB(3) PFB(4) PFB(5) PFB(6) PFB(7) PFB(8)
    PFB(9) PFB(10) PFB(11) PFB(12) PFB(13) PFB(14) PFB(15) PFB(16)
    // issue next-interval p loads (stay in flight across BAR)
    {
      const int t0n = t0 - 16;
#define QLDN(k) qn##k = po[dbase(t0n + 2 - (k)) + r];
      QLDN(0) QLDN(1) QLDN(2) QLDN(3) QLDN(4) QLDN(5) QLDN(6) QLDN(7) QLDN(8)
      QLDN(9) QLDN(10) QLDN(11) QLDN(12) QLDN(13) QLDN(14) QLDN(15) QLDN(16)
    }

#define BSTEP(m, QM1, REN, RPN) { \
    const int t = t0 - (m); \
    const float reb = reaP; \
    const float rea = dpp_shl1_f(ea, (REN)); \
    const uint32_t rq2 = rqP; \
    const uint32_t rq1 = dpp_shl1_u((QM1), (RPN)); \
    const bool vd = (unsigned)(t - r - 1) < 512u; \
    const bool rt = (unsigned)(t - r) < 512u; \
    const float pd = (float)(rq2 & 0xffffu) * inv16; \
    const float pu = (float)(rq1 >> 16) * inv16; \
    const float pl = 1.0f - (float)((QM1) & 0xffffu) * inv16 - (float)((QM1) >> 16) * inv16; \
    float n = (rless ? rea * pu : 0.0f) + ((rless && rt) ? reb * pd : 0.0f) + (rt ? ea * pl : 0.0f); \
    n = vd ? n : 0.0f; \
    if (vd) ews[dbase(t) + r] = n; \
    if (wgt0 && lane0) { const int sl = t & 63; Ering[w - 1][sl] = n; Ering[w - 1][sl + 64] = n; } \
    ea = n; reaP = rea; rqP = rq1; \
  }
    BSTEP(0, q1, rE1, rP1) BSTEP(1, q2, rE2, rP2) BSTEP(2, q3, rE3, rP3) BSTEP(3, q4, rE4, rP4)
    BSTEP(4, q5, rE5, rP5) BSTEP(5, q6, rE6, rP6) BSTEP(6, q7, rE7, rP7) BSTEP(7, q8, rE8, rP8)
    BSTEP(8, q9, rE9, rP9) BSTEP(9, q10, rE10, rP10) BSTEP(10, q11, rE11, rP11) BSTEP(11, q12, rE12, rP12)
    BSTEP(12, q13, rE13, rP13) BSTEP(13, q14, rE14, rP14) BSTEP(14, q15, rE15, rP15) BSTEP(15, q16, rE16, rP16)

    // publish own p-packs for downstream reader (boundary row = this wave's lane0 row)
    if (wgt0 && lane0) {
#define PWR(k) { const int sl = (t0 + 2 - (k)) & 63; Pring[w - 1][sl] = q##k; Pring[w - 1][sl + 64] = q##k; }
      PWR(0) PWR(1) PWR(2) PWR(3) PWR(4) PWR(5) PWR(6) PWR(7) PWR(8)
      PWR(9) PWR(10) PWR(11) PWR(12) PWR(13) PWR(14) PWR(15) PWR(16)
    }
    // roll pipelined q
#define QMV(k) q##k = qn##k;
    QMV(0) QMV(1) QMV(2) QMV(3) QMV(4) QMV(5) QMV(6) QMV(7) QMV(8)
    QMV(9) QMV(10) QMV(11) QMV(12) QMV(13) QMV(14) QMV(15) QMV(16)
    BAR();
  }
}

// ---------------------------------------------------------------------------
// K5: transpose diag-major E (ws) -> row-major out. 64x64 cell tiles.
// ---------------------------------------------------------------------------
__global__ __launch_bounds__(256) void k_tr(const float* __restrict__ ews, float* __restrict__ out) {
  const int blk = blockIdx.x;
  const int b = blk >> 6, ti = (blk >> 3) & 7, tj = blk & 7;
  const float* src = ews + (size_t)b * NCELL;
  float* dst = out + (size_t)b * NCELL;
  __shared__ float tile[64][68];
  const int i0 = ti * 64, j0 = tj * 64;
  const int t = threadIdx.x;
  const int sub = t >> 6, lane = t & 63;
  for (int k = sub; k < 127; k += 4) {
    const int d = i0 + j0 + 2 + k;
    const int ilo_t = max(i0 + 1, d - (j0 + 64));
    const int ihi_t = min(i0 + 64, d - (j0 + 1));
    const int i = ilo_t + lane;
    if (i <= ihi_t) {
      const int lo = (d > 513) ? d - 512 : 1;
      tile[i - 1 - i0][d - i - 1 - j0] = src[offd(d) - lo + i];
    }
  }
  __syncthreads();
  const int rr = t >> 2, q = (t & 3) * 16;
  float4* drow = (float4*)&dst[(size_t)(i0 + rr) * 512 + j0 + q];
  const float* srow = &tile[rr][q];
  drow[0] = *(const float4*)&srow[0];
  drow[1] = *(const float4*)&srow[4];
  drow[2] = *(const float4*)&srow[8];
  drow[3] = *(const float4*)&srow[12];
}

// ---------------------------------------------------------------------------
extern "C" void kernel_launch(void* const* d_in, const int* in_sizes, int n_in,
                              void* d_out, int out_size, void* d_ws, size_t ws_size,
                              hipStream_t stream) {
  const int* x = (const int*)d_in[0];
  const int* y = (const int*)d_in[1];
  const float* We = (const float*)d_in[2];
  const float* Wp = (const float*)d_in[3];
  const float* bp = (const float*)d_in[4];
  const float* Wg = (const float*)d_in[5];
  const float* bg = (const float*)d_in[6];
  float* out = (float*)d_out;

  float* ws = (float*)d_ws;
  float* T = ws;              // 22*512 floats
  float* G = ws + 11264;      // 814 (22x37 padded)
  float* u = G + 814;         // 22
  float* v = u + 22;          // 22
  float* A = v + 22;          // 16
  float* ews = (float*)((char*)d_ws + (1 << 20));  // 16 MiB diag-major E

  k_T<<<22, 512, 0, stream>>>(We, Wp, bp, T);
  k_G<<<1, 512, 0, stream>>>(T, Wg, G, u, v);
  k_A<<<16, 256, 0, stream>>>(x, y, u, v, bg, A);
  k_nw<<<16, 512, 0, stream>>>(x, y, G, A, (uint32_t*)d_out, ews);
  k_tr<<<16 * 64, 256, 0, stream>>>(ews, out);
}

// Round 10
// 532.983 us; speedup vs baseline: 1.4657x; 1.0058x over previous
//
#include <hip/hip_runtime.h>
#include <stdint.h>

#define NEGF (-1.0e8f)
#define NCELL (512 * 512)
#define INVLN2 1.4426950408889634f
#define NIV 71  // intervals of 16 diagonals; skew 16/wave

// raw barrier: LDS ordering only (never drains vmcnt -> global ops stay in flight)
#define BAR() asm volatile("s_waitcnt lgkmcnt(0)\n\ts_barrier" ::: "memory")

__device__ __forceinline__ float exp2f_(float x) {
#if __has_builtin(__builtin_amdgcn_exp2f)
  return __builtin_amdgcn_exp2f(x);
#else
  return exp2f(x);
#endif
}
__device__ __forceinline__ float log2f_(float x) {
#if __has_builtin(__builtin_amdgcn_logf)
  return __builtin_amdgcn_logf(x);
#else
  return log2f(x);
#endif
}
__device__ __forceinline__ uint32_t pknorm16(float a, float b) {
#if __has_builtin(__builtin_amdgcn_cvt_pknorm_u16)
  typedef unsigned short u2v __attribute__((ext_vector_type(2)));
  union { u2v v; uint32_t u; } cv;
  cv.v = __builtin_amdgcn_cvt_pknorm_u16(a, b);
  return cv.u;
#else
  uint32_t pa = (uint32_t)(a * 65535.0f + 0.5f);
  uint32_t pb = (uint32_t)(b * 65535.0f + 0.5f);
  return pa | (pb << 16);
#endif
}

// DPP wave shifts: 0x138 wave_shr:1 (lane l <- l-1, lane0 <- old), 0x130 wave_shl:1 (lane l <- l+1, lane63 <- old)
__device__ __forceinline__ float dpp_shr1_f(float src, float old0) {
  return __int_as_float(__builtin_amdgcn_update_dpp(
      __float_as_int(old0), __float_as_int(src), 0x138, 0xF, 0xF, false));
}
__device__ __forceinline__ float dpp_shl1_f(float src, float old63) {
  return __int_as_float(__builtin_amdgcn_update_dpp(
      __float_as_int(old63), __float_as_int(src), 0x130, 0xF, 0xF, false));
}
__device__ __forceinline__ uint32_t dpp_shl1_u(uint32_t src, uint32_t old63) {
  return (uint32_t)__builtin_amdgcn_update_dpp((int)old63, (int)src, 0x130, 0xF, 0xF, false);
}

// offset of diagonal d; lo(d)=max(1,d-512)
__device__ __forceinline__ int offd(int d) {
  return (d <= 513) ? (((d - 2) * (d - 1)) >> 1)
                    : (NCELL - (((1025 - d) * (1026 - d)) >> 1));
}
__device__ __forceinline__ int dbase(int d) {
  const int lo = (d > 513) ? d - 512 : 1;
  return offd(d) - lo;
}

// forward softmax-LSE cell (base-2 domain)
__device__ __forceinline__ void fcell(float& nv, uint32_t& pk, float dg, float up0,
                                      float lf0, float th, float A2) {
  float up = up0 + A2, lf = lf0 + A2;
  float mx = fmaxf(fmaxf(dg, up), lf);
  float ed = exp2f_(dg - mx), eu = exp2f_(up - mx), el = exp2f_(lf - mx);
  float s = ed + eu + el;
  nv = th + mx + log2f_(s);
  float rs = __builtin_amdgcn_rcpf(s);
  pk = pknorm16(ed * rs, eu * rs);
}

// ---------------------------------------------------------------------------
// K1: T[22][512] = W_embed @ W_proj + b_proj
// ---------------------------------------------------------------------------
__global__ void k_T(const float* __restrict__ We, const float* __restrict__ Wp,
                    const float* __restrict__ bp, float* __restrict__ T) {
  int a = blockIdx.x, c = threadIdx.x;
  __shared__ float e[512];
  e[c] = We[a * 512 + c];
  __syncthreads();
  float acc = bp[c];
#pragma unroll 8
  for (int k = 0; k < 512; ++k) acc = fmaf(e[k], Wp[k * 512 + c], acc);
  T[a * 512 + c] = acc;
}

// ---------------------------------------------------------------------------
// K2: G2[a][a2] (stride 37 for LDS bank spread) = (T T^T)/ln2 ; u,v gap LUTs
// ---------------------------------------------------------------------------
__global__ void k_G(const float* __restrict__ T, const float* __restrict__ Wg,
                    float* __restrict__ G, float* __restrict__ u, float* __restrict__ v) {
  __shared__ float Ts[22 * 516];
  for (int k = threadIdx.x; k < 22 * 512; k += 512) {
    int a = k >> 9, c = k & 511;
    Ts[a * 516 + c] = T[k];
  }
  __syncthreads();
  for (int idx = threadIdx.x; idx < 528; idx += 512) {
    float s = 0.f;
    if (idx < 484) {
      int a = idx / 22, a2 = idx - 22 * a;
      const float* pa = &Ts[a * 516];
      const float* pb = &Ts[a2 * 516];
      for (int c = 0; c < 512; ++c) s = fmaf(pa[c], pb[c], s);
      G[a * 37 + a2] = s * INVLN2;  // padded row stride 37
    } else if (idx < 506) {
      int a = idx - 484;
      const float* pa = &Ts[a * 516];
      for (int c = 0; c < 512; ++c) s = fmaf(pa[c], Wg[c], s);
      u[a] = s;
    } else {
      int a = idx - 506;
      const float* pa = &Ts[a * 516];
      for (int c = 0; c < 512; ++c) s = fmaf(pa[c], Wg[512 + c], s);
      v[a] = s;
    }
  }
}

// ---------------------------------------------------------------------------
// K3: A2[b]
// ---------------------------------------------------------------------------
__global__ void k_A(const int* __restrict__ x, const int* __restrict__ y,
                    const float* __restrict__ u, const float* __restrict__ v,
                    const float* __restrict__ bg, float* __restrict__ A) {
  int b = blockIdx.x, t = threadIdx.x;
  const int* xb = x + b * 512;
  const int* yb = y + b * 512;
  float s = u[xb[t]] + u[xb[t + 256]] + v[yb[t]] + v[yb[t + 256]];
  for (int o = 32; o > 0; o >>= 1) s += __shfl_down(s, o, 64);
  __shared__ float w[4];
  if ((t & 63) == 0) w[t >> 6] = s;
  __syncthreads();
  if (t == 0) A[b] = ((w[0] + w[1] + w[2] + w[3]) * (1.0f / 512.0f) + bg[0]) * INVLN2;
}

// ---------------------------------------------------------------------------
// K4: skewed 8-wave pipeline DP with per-wave active-window gating.
//     512 threads, 1 row/lane (r=64w+lane+1). Inactive intervals: BAR only.
// ---------------------------------------------------------------------------
__global__ __launch_bounds__(512) void k_nw(const int* __restrict__ x, const int* __restrict__ y,
                                            const float* __restrict__ G,
                                            const float* __restrict__ Aarr,
                                            uint32_t* __restrict__ po,
                                            float* __restrict__ ews) {
  const int tid = threadIdx.x;
  const int w = __builtin_amdgcn_readfirstlane(tid) >> 6;  // wave id, forced SGPR
  const int lane = tid & 63;
  __shared__ float Gl[814];       // 22 x 37
  __shared__ int ysPad[1856];     // ys values padded; index = dn-1-r + 640
  __shared__ float Vring[8][128];     // Vring[w] read by wave w (fwd); written by w-1
  __shared__ float Ering[8][128];     // Ering[w] read by wave w (bwd); written by w+1
  __shared__ uint32_t Pring[8][128];  // same indexing as Ering

  const int b = blockIdx.x;
  const int* xbp = x + b * 512;
  const int* ybp = y + b * 512;
  // ysPad: zero pads + values at [640, 1152)
  for (int k = tid; k < 640; k += 512) ysPad[k] = 0;
  for (int k = 1152 + tid; k < 1856; k += 512) ysPad[k] = 0;
  ysPad[640 + tid] = ybp[tid];
  for (int k = tid; k < 814; k += 512) Gl[k] = G[k];
  // full ring init: border values (NEGF for V, 0 for E/p) — never-written slots
  // must read as borders under early-exit gating
  for (int k = tid; k < 1024; k += 512) {
    ((float*)Vring)[k] = NEGF;
    ((float*)Ering)[k] = 0.0f;
    ((uint32_t*)Pring)[k] = 0u;
  }
  const float A2 = Aarr[b];
  const int r = 64 * w + lane + 1;
  const int xr = xbp[r - 1] * 37;
  const bool lane0 = (lane == 0), lane63 = (lane == 63);
  const bool wgt0 = (w > 0), wlt7 = (w < 7);
  const bool rless = (r < 512);
  po += (size_t)b * NCELL;
  ews += (size_t)b * NCELL;
  __syncthreads();

  // ================= forward =================
  const int ivLoF = 5 * w;                                      // first active interval
  const int ivHiF = (5 * w + 35 < NIV - 1) ? 5 * w + 35 : NIV - 1;
  const int dnP0 = 2 + 64 * w;  // dn0 at ivLoF

  float th0, th1, th2, th3, th4, th5, th6, th7, th8, th9, th10, th11, th12, th13, th14, th15;
#define PROTH(m) { const int ix = (dnP0 + (m)) + 639 - r; th##m = Gl[xr + ysPad[ix]]; }
  PROTH(0) PROTH(1) PROTH(2) PROTH(3) PROTH(4) PROTH(5) PROTH(6) PROTH(7)
  PROTH(8) PROTH(9) PROTH(10) PROTH(11) PROTH(12) PROTH(13) PROTH(14) PROTH(15)

  float va = NEGF, rupP = NEGF;
#pragma unroll 1
  for (int iv = 0; iv < NIV; ++iv) {
    if (iv >= ivLoF && iv <= ivHiF) {
      const int dn0 = 2 - 16 * w + 16 * iv;  // scalar (w scalar, iv uniform)
      const int sV = (dn0 - 1) & 63;
      const float* Vr2 = &Vring[w][sV];
      float rv1, rv2, rv3, rv4, rv5, rv6, rv7, rv8, rv9, rv10, rv11, rv12, rv13, rv14, rv15, rv16;
#define PFV(k) rv##k = Vr2[(k) - 1];
      PFV(1) PFV(2) PFV(3) PFV(4) PFV(5) PFV(6) PFV(7) PFV(8)
      PFV(9) PFV(10) PFV(11) PFV(12) PFV(13) PFV(14) PFV(15) PFV(16)

#define FSTEP(m, RVN) { \
    const int dn = dn0 + (m); \
    float rdg = rupP; \
    if ((m) == 0 && w == 0 && iv == 0) rdg = lane0 ? 0.0f : rdg; /* V[0,0]=0 corner */ \
    const float rup = dpp_shr1_f(va, (RVN)); \
    float nv; uint32_t pk; \
    fcell(nv, pk, rdg, rup, va, th##m, A2); \
    const bool vv = (unsigned)(dn - r - 1) < 512u; \
    nv = vv ? nv : NEGF; \
    if (vv) po[dbase(dn) + r] = pk; \
    if (wlt7 && lane63) { const int sl = dn & 63; Vring[w + 1][sl] = nv; Vring[w + 1][sl + 64] = nv; } \
    { const int ix = dn + 655 - r; th##m = Gl[xr + ysPad[ix]]; } \
    va = nv; rupP = rup; \
  }
      FSTEP(0, rv1) FSTEP(1, rv2) FSTEP(2, rv3) FSTEP(3, rv4)
      FSTEP(4, rv5) FSTEP(5, rv6) FSTEP(6, rv7) FSTEP(7, rv8)
      FSTEP(8, rv9) FSTEP(9, rv10) FSTEP(10, rv11) FSTEP(11, rv12)
      FSTEP(12, rv13) FSTEP(13, rv14) FSTEP(14, rv15) FSTEP(15, rv16)
    }
    BAR();
  }

  // ================= transition: drain p stores once =================
  asm volatile("s_waitcnt vmcnt(0)" ::: "memory");
  __threadfence_block();
  __syncthreads();

  // ================= backward =================
  const float inv16 = 1.0f / 65535.0f;
  const bool w7 = (w == 7);
  const int ivLoB = (34 - 5 * w > 0) ? 34 - 5 * w : 0;
  const int ivHiB = 70 - 5 * w;
  float ea = (w7 && lane63) ? 1.0f : 0.0f;
  float reaP = 0.0f;
  uint32_t rqP = 0u;
  if (w7 && lane63) ews[NCELL - 1] = 1.0f;  // E(512,512) seed (diag 1024)

  uint32_t q0, q1, q2, q3, q4, q5, q6, q7, q8, q9, q10, q11, q12, q13, q14, q15, q16;
  uint32_t qn0, qn1, qn2, qn3, qn4, qn5, qn6, qn7, qn8, qn9, qn10, qn11, qn12, qn13, qn14, qn15, qn16;
  {
    const int t0p = 1135 - 16 * w - 16 * ivLoB;  // first active interval's t0
#define QLD0(k) q##k = po[dbase(t0p + 2 - (k)) + r];
    QLD0(0) QLD0(1) QLD0(2) QLD0(3) QLD0(4) QLD0(5) QLD0(6) QLD0(7) QLD0(8)
    QLD0(9) QLD0(10) QLD0(11) QLD0(12) QLD0(13) QLD0(14) QLD0(15) QLD0(16)
  }

#pragma unroll 1
  for (int iv = 0; iv < NIV; ++iv) {
    if (iv >= ivLoB && iv <= ivHiB) {
      const int t0 = 1135 - 16 * w - 16 * iv;  // scalar
      const int sE = (t0 - 14) & 63;
      const float* Er2 = &Ering[w][sE];
      const uint32_t* Pr2 = &Pring[w][sE];
      float rE1, rE2, rE3, rE4, rE5, rE6, rE7, rE8, rE9, rE10, rE11, rE12, rE13, rE14, rE15, rE16;
      uint32_t rP1, rP2, rP3, rP4, rP5, rP6, rP7, rP8, rP9, rP10, rP11, rP12, rP13, rP14, rP15, rP16;
#define PFB(k) rE##k = Er2[16 - (k)]; rP##k = Pr2[16 - (k)];
      PFB(1) PFB(2) PFB(3) PFB(4) PFB(5) PFB(6) PFB(7) PFB(8)
      PFB(9) PFB(10) PFB(11) PFB(12) PFB(13) PFB(14) PFB(15) PFB(16)
      // issue next-interval p loads (stay in flight across BAR)
      if (iv < ivHiB) {
        const int t0n = t0 - 16;
#define QLDN(k) qn##k = po[dbase(t0n + 2 - (k)) + r];
        QLDN(0) QLDN(1) QLDN(2) QLDN(3) QLDN(4) QLDN(5) QLDN(6) QLDN(7) QLDN(8)
        QLDN(9) QLDN(10) QLDN(11) QLDN(12) QLDN(13) QLDN(14) QLDN(15) QLDN(16)
      }

#define BSTEP(m, QM1, REN, RPN) { \
    const int t = t0 - (m); \
    const float reb = reaP; \
    const float rea = dpp_shl1_f(ea, (REN)); \
    const uint32_t rq2 = rqP; \
    const uint32_t rq1 = dpp_shl1_u((QM1), (RPN)); \
    const bool vd = (unsigned)(t - r - 1) < 512u; \
    const bool rt = (unsigned)(t - r) < 512u; \
    const float pd = (float)(rq2 & 0xffffu) * inv16; \
    const float pu = (float)(rq1 >> 16) * inv16; \
    const float pl = 1.0f - (float)((QM1) & 0xffffu) * inv16 - (float)((QM1) >> 16) * inv16; \
    float n = (rless ? rea * pu : 0.0f) + ((rless && rt) ? reb * pd : 0.0f) + (rt ? ea * pl : 0.0f); \
    n = vd ? n : 0.0f; \
    if (vd) ews[dbase(t) + r] = n; \
    if (wgt0 && lane0) { const int sl = t & 63; Ering[w - 1][sl] = n; Ering[w - 1][sl + 64] = n; } \
    ea = n; reaP = rea; rqP = rq1; \
  }
      BSTEP(0, q1, rE1, rP1) BSTEP(1, q2, rE2, rP2) BSTEP(2, q3, rE3, rP3) BSTEP(3, q4, rE4, rP4)
      BSTEP(4, q5, rE5, rP5) BSTEP(5, q6, rE6, rP6) BSTEP(6, q7, rE7, rP7) BSTEP(7, q8, rE8, rP8)
      BSTEP(8, q9, rE9, rP9) BSTEP(9, q10, rE10, rP10) BSTEP(10, q11, rE11, rP11) BSTEP(11, q12, rE12, rP12)
      BSTEP(12, q13, rE13, rP13) BSTEP(13, q14, rE14, rP14) BSTEP(14, q15, rE15, rP15) BSTEP(15, q16, rE16, rP16)

      // publish own p-packs for downstream reader (boundary row = this wave's lane0 row)
      if (wgt0 && lane0) {
#define PWR(k) { const int sl = (t0 + 2 - (k)) & 63; Pring[w - 1][sl] = q##k; Pring[w - 1][sl + 64] = q##k; }
        PWR(0) PWR(1) PWR(2) PWR(3) PWR(4) PWR(5) PWR(6) PWR(7) PWR(8)
        PWR(9) PWR(10) PWR(11) PWR(12) PWR(13) PWR(14) PWR(15) PWR(16)
      }
      // roll pipelined q (only when next interval was prefetched)
      if (iv < ivHiB) {
#define QMV(k) q##k = qn##k;
        QMV(0) QMV(1) QMV(2) QMV(3) QMV(4) QMV(5) QMV(6) QMV(7) QMV(8)
        QMV(9) QMV(10) QMV(11) QMV(12) QMV(13) QMV(14) QMV(15) QMV(16)
      }
    }
    BAR();
  }
}

// ---------------------------------------------------------------------------
// K5: transpose diag-major E (ws) -> row-major out. 64x64 cell tiles.
// ---------------------------------------------------------------------------
__global__ __launch_bounds__(256) void k_tr(const float* __restrict__ ews, float* __restrict__ out) {
  const int blk = blockIdx.x;
  const int b = blk >> 6, ti = (blk >> 3) & 7, tj = blk & 7;
  const float* src = ews + (size_t)b * NCELL;
  float* dst = out + (size_t)b * NCELL;
  __shared__ float tile[64][68];
  const int i0 = ti * 64, j0 = tj * 64;
  const int t = threadIdx.x;
  const int sub = t >> 6, lane = t & 63;
  for (int k = sub; k < 127; k += 4) {
    const int d = i0 + j0 + 2 + k;
    const int ilo_t = max(i0 + 1, d - (j0 + 64));
    const int ihi_t = min(i0 + 64, d - (j0 + 1));
    const int i = ilo_t + lane;
    if (i <= ihi_t) {
      const int lo = (d > 513) ? d - 512 : 1;
      tile[i - 1 - i0][d - i - 1 - j0] = src[offd(d) - lo + i];
    }
  }
  __syncthreads();
  const int rr = t >> 2, q = (t & 3) * 16;
  float4* drow = (float4*)&dst[(size_t)(i0 + rr) * 512 + j0 + q];
  const float* srow = &tile[rr][q];
  drow[0] = *(const float4*)&srow[0];
  drow[1] = *(const float4*)&srow[4];
  drow[2] = *(const float4*)&srow[8];
  drow[3] = *(const float4*)&srow[12];
}

// ---------------------------------------------------------------------------
extern "C" void kernel_launch(void* const* d_in, const int* in_sizes, int n_in,
                              void* d_out, int out_size, void* d_ws, size_t ws_size,
                              hipStream_t stream) {
  const int* x = (const int*)d_in[0];
  const int* y = (const int*)d_in[1];
  const float* We = (const float*)d_in[2];
  const float* Wp = (const float*)d_in[3];
  const float* bp = (const float*)d_in[4];
  const float* Wg = (const float*)d_in[5];
  const float* bg = (const float*)d_in[6];
  float* out = (float*)d_out;

  float* ws = (float*)d_ws;
  float* T = ws;              // 22*512 floats
  float* G = ws + 11264;      // 814 (22x37 padded)
  float* u = G + 814;         // 22
  float* v = u + 22;          // 22
  float* A = v + 22;          // 16
  float* ews = (float*)((char*)d_ws + (1 << 20));  // 16 MiB diag-major E

  k_T<<<22, 512, 0, stream>>>(We, Wp, bp, T);
  k_G<<<1, 512, 0, stream>>>(T, Wg, G, u, v);
  k_A<<<16, 256, 0, stream>>>(x, y, u, v, bg, A);
  k_nw<<<16, 512, 0, stream>>>(x, y, G, A, (uint32_t*)d_out, ews);
  k_tr<<<16 * 64, 256, 0, stream>>>(ews, out);
}